// Round 12
// baseline (727.186 us; speedup 1.0000x reference)
//
#include <hip/hip_runtime.h>
#include <hip/hip_cooperative_groups.h>
#include <hip/hip_bf16.h>
#include <math.h>

typedef __hip_bfloat16 bf16;
namespace cg = cooperative_groups;

#define FEAT 128
#define NRBF 20
#define CUTOFF_F 5.0f
#define KSCALE 0.62831853071795864769f  // pi / 5
#define NB 4096
#define INV_H 819.0f                    // (NB-1)/CUTOFF
#define H_STEP 0.001221001221001221f    // CUTOFF/(NB-1)
#define EPT_MAX 8

__device__ __forceinline__ float b2f(bf16 x) { return __bfloat162float(x); }
__device__ __forceinline__ bf16 f2b(float x) { return __float2bfloat16(x); }
__device__ __forceinline__ float us2f(unsigned short u) {
    return __uint_as_float(((unsigned)u) << 16);
}

template<int F32>
__device__ __forceinline__ float LD(const void* p, size_t i) {
    if (F32) return ((const float*)p)[i];
    return b2f(((const bf16*)p)[i]);
}
template<int F32>
__device__ __forceinline__ void ST(void* p, size_t i, float v) {
    if (F32) ((float*)p)[i] = v;
    else ((bf16*)p)[i] = f2b(v);
}

__device__ __forceinline__ int get_dst(const int* nb, int e, int is64) {
    return is64 ? nb[4 * e] : nb[2 * e];
}
__device__ __forceinline__ int get_src(const int* nb, int e, int is64) {
    return is64 ? nb[4 * e + 2] : nb[2 * e + 1];
}
__device__ __forceinline__ int clampi(int v, int n) {
    return v < 0 ? 0 : (v >= n ? n - 1 : v);
}

__device__ __forceinline__ float tab_entry(const void* Wd, const void* bd, int F32,
                                           int bb, int c) {
    const float d = fmaxf(bb * H_STEP, 1e-7f);
    const float x = d * KSCALE;
    const float s1 = sinf(x);
    const float c1 = cosf(x);
    const float env = (d < CUTOFF_F) ? (0.5f * (c1 + 1.0f)) : 0.0f;
    const float invd = 1.0f / d;
    float acc = F32 ? ((const float*)bd)[c] : b2f(((const bf16*)bd)[c]);
    const float tc = 2.0f * c1;
    float skm2 = 0.f, skm1 = s1;
    float g0 = s1 * invd;
    {
        const float w = F32 ? ((const float*)Wd)[c] : b2f(((const bf16*)Wd)[c]);
        acc = fmaf(g0, w, acc);
    }
    #pragma unroll
    for (int k = 1; k < NRBF; ++k) {
        const float sk = fmaf(tc, skm1, -skm2);
        const float gk = sk * invd;
        const float w = F32 ? ((const float*)Wd)[(size_t)k * 384 + c]
                            : b2f(((const bf16*)Wd)[(size_t)k * 384 + c]);
        acc = fmaf(gk, w, acc);
        skm2 = skm1; skm1 = sk;
    }
    return acc * env;
}

// ================== cooperative fused CSR build (mode C) ==================
// P0 zero+sniff | S | P1 hist (d,j kept in regs) + table | S | P2a block sums
// | S | P2c scan+write offsets/cursor | S | P3 scatter {src_ids, u4}
__global__ __launch_bounds__(256) void csr_coop_kernel(
        const void* s_ptr, const int* nbrs, const void* r_ij,
        int* flags, int* counts, int* offsets, int* cursor,
        int* src_ids, float4* u_env, const void* Wd, const void* bd,
        bf16* tab, int* partials, int nE, int nN) {
    cg::grid_group grid = cg::this_grid();
    const int t   = threadIdx.x;
    const int b   = blockIdx.x;
    const int nb  = gridDim.x;
    const int tid = b * 256 + t;
    const int tot = nb * 256;

    // ---- P0: zero counts + sniff dtypes ----
    for (int i = tid; i < nN; i += tot) counts[i] = 0;
    if (tid == 0) {
        const unsigned* u = (const unsigned*)s_ptr;
        int hits = 0;
        for (int i = 0; i < 64; ++i) {
            unsigned ef = (u[i] >> 7) & 0xFF;
            hits += (ef >= 110 && ef <= 135) ? 1 : 0;
        }
        flags[0] = (hits < 32) ? 1 : 0;
        int lim = 2 * nE; if (lim > 128) lim = 128;
        int allz = 1;
        for (int i = 1; i < lim; i += 2) allz &= (nbrs[i] == 0);
        flags[1] = allz;
    }
    grid.sync();

    const int F32  = flags[0];
    const int is64 = flags[1];

    // ---- P1: hist atomics (keep d,j in regs, static indexing) + table ----
    int dre[EPT_MAX], jre[EPT_MAX];
    #pragma unroll
    for (int k = 0; k < EPT_MAX; ++k) {
        const int e = tid + k * tot;
        int dd = -1, jj = -1;
        if (e < nE) {
            dd = clampi(get_dst(nbrs, e, is64), nN);
            jj = clampi(get_src(nbrs, e, is64), nN);
            atomicAdd(&counts[dd], 1);
        }
        dre[k] = dd; jre[k] = jj;
    }
    for (int i = tid; i < NB * 384; i += tot) {
        const int bb = i / 384, c = i - bb * 384;
        tab[i] = f2b(tab_entry(Wd, bd, F32, bb, c));
    }
    grid.sync();

    // ---- P2a: per-block partial sums of counts chunk ----
    const int chunk = (nN + nb - 1) / nb;
    if (t == 0) {
        int s = 0;
        const int base = b * chunk;
        for (int c = 0; c < chunk; ++c) {
            const int idx = base + c;
            if (idx < nN) s += counts[idx];
        }
        partials[b] = s;
    }
    grid.sync();

    // ---- P2c: each block computes its prefix and writes offsets/cursor ----
    {
        __shared__ int red[256];
        int s = 0;
        for (int i = t; i < b; i += 256) s += partials[i];
        red[t] = s;
        __syncthreads();
        for (int o = 128; o; o >>= 1) {
            if (t < o) red[t] += red[t + o];
            __syncthreads();
        }
        if (t == 0) {
            int run = red[0];
            const int base = b * chunk;
            for (int c = 0; c < chunk; ++c) {
                const int idx = base + c;
                if (idx < nN) {
                    offsets[idx] = run; cursor[idx] = run;
                    run += counts[idx];
                }
            }
            if (b == nb - 1) offsets[nN] = run;
        }
    }
    grid.sync();

    // ---- P3: scatter src_ids + u4{unit, binf} ----
    #pragma unroll
    for (int k = 0; k < EPT_MAX; ++k) {
        const int e = tid + k * tot;
        if (e < nE) {
            const int dd = dre[k], jj = jre[k];
            float rx, ry, rz;
            if (F32) {
                rx = ((const float*)r_ij)[(size_t)3 * e + 0];
                ry = ((const float*)r_ij)[(size_t)3 * e + 1];
                rz = ((const float*)r_ij)[(size_t)3 * e + 2];
            } else {
                rx = b2f(((const bf16*)r_ij)[(size_t)3 * e + 0]);
                ry = b2f(((const bf16*)r_ij)[(size_t)3 * e + 1]);
                rz = b2f(((const bf16*)r_ij)[(size_t)3 * e + 2]);
            }
            const float d2   = rx * rx + ry * ry + rz * rz + 3e-15f;
            const float invd = rsqrtf(d2);
            const float dd_f = d2 * invd;
            int pos = atomicAdd(&cursor[dd], 1);
            pos = clampi(pos, nE);
            src_ids[pos] = jj;
            u_env[pos] = make_float4(rx * invd, ry * invd, rz * invd, dd_f * INV_H);
        }
    }
}

// ================== fallback / mode A,B kernels (unchanged) ==================

__global__ void init_kernel(const void* __restrict__ s_ptr, const int* __restrict__ nbrs32,
                            int nE, int* __restrict__ flags, int* __restrict__ counts, int nN) {
    int t = blockIdx.x * blockDim.x + threadIdx.x;
    if (t < nN) counts[t] = 0;
    if (t == 0) {
        const unsigned* u = (const unsigned*)s_ptr;
        int hits = 0;
        for (int i = 0; i < 64; ++i) {
            unsigned ef = (u[i] >> 7) & 0xFF;
            hits += (ef >= 110 && ef <= 135) ? 1 : 0;
        }
        flags[0] = (hits < 32) ? 1 : 0;
        int lim = 2 * nE; if (lim > 128) lim = 128;
        int allz = 1;
        for (int i = 1; i < lim; i += 2) allz &= (nbrs32[i] == 0);
        flags[1] = allz;
    }
}

__global__ void hist_kernel(const int* __restrict__ nbrs, const int* __restrict__ flags,
                            int* __restrict__ counts, int nE, int nN) {
    int e = blockIdx.x * blockDim.x + threadIdx.x;
    if (e < nE) {
        int d = clampi(get_dst(nbrs, e, flags[1]), nN);
        atomicAdd(&counts[d], 1);
    }
}

__global__ __launch_bounds__(1024) void scan_kernel(const int* __restrict__ counts,
        int* __restrict__ offsets, int* __restrict__ cursor, int nN) {
    __shared__ int part[1024];
    const int t = threadIdx.x;
    const int chunk = (nN + 1023) / 1024;
    const int base = t * chunk;
    int local[32];
    int sum = 0;
    for (int c = 0; c < chunk && c < 32; ++c) {
        int idx = base + c;
        int v = (idx < nN) ? counts[idx] : 0;
        local[c] = v;
        sum += v;
    }
    part[t] = sum;
    __syncthreads();
    for (int off = 1; off < 1024; off <<= 1) {
        int add = (t >= off) ? part[t - off] : 0;
        __syncthreads();
        part[t] += add;
        __syncthreads();
    }
    int run = part[t] - sum;
    for (int c = 0; c < chunk && c < 32; ++c) {
        int idx = base + c;
        if (idx < nN) { offsets[idx] = run; cursor[idx] = run; run += local[c]; }
    }
    if (t == 1023) offsets[nN] = part[1023];
}

__global__ __launch_bounds__(384) void prep_kernel(const void* __restrict__ Wd,
        const void* __restrict__ bd, float* __restrict__ WdT, const int* __restrict__ flags) {
    const int c = threadIdx.x;
    const int F32 = flags[0];
    if (F32) {
        for (int k = 0; k < NRBF; ++k) WdT[c * 24 + k] = ((const float*)Wd)[k * 384 + c];
        WdT[c * 24 + 20] = ((const float*)bd)[c];
    } else {
        for (int k = 0; k < NRBF; ++k) WdT[c * 24 + k] = b2f(((const bf16*)Wd)[k * 384 + c]);
        WdT[c * 24 + 20] = b2f(((const bf16*)bd)[c]);
    }
    WdT[c * 24 + 21] = 0.f; WdT[c * 24 + 22] = 0.f; WdT[c * 24 + 23] = 0.f;
}

__global__ __launch_bounds__(384) void build_table_kernel(const void* __restrict__ Wd,
        const void* __restrict__ bd, bf16* __restrict__ tab, const int* __restrict__ flags) {
    const int b = blockIdx.x;
    const int c = threadIdx.x;
    tab[(size_t)b * 384 + c] = f2b(tab_entry(Wd, bd, flags[0], b, c));
}

template<int F32, int MODE>
__device__ void pre_scatter_body(const void* __restrict__ r_ij, const int* __restrict__ nbrs,
        int is64, int* __restrict__ cursor, int* __restrict__ src_ids,
        float4* __restrict__ u_env, int* __restrict__ pos_of_e, float* __restrict__ gbuf,
        int e, int nE, int nN) {
    const int d = clampi(get_dst(nbrs, e, is64), nN);
    const int j = clampi(get_src(nbrs, e, is64), nN);
    int pos = atomicAdd(&cursor[d], 1);
    pos = clampi(pos, nE);
    src_ids[pos] = j;

    const float rx = LD<F32>(r_ij, (size_t)3 * e + 0);
    const float ry = LD<F32>(r_ij, (size_t)3 * e + 1);
    const float rz = LD<F32>(r_ij, (size_t)3 * e + 2);
    const float d2   = rx * rx + ry * ry + rz * rz + 3e-15f;
    const float invd = rsqrtf(d2);
    const float dd   = d2 * invd;

    if (MODE == 2) {
        u_env[pos] = make_float4(rx * invd, ry * invd, rz * invd, dd * INV_H);
        return;
    }

    const float x  = dd * KSCALE;
    const float c1 = F32 ? cosf(x) : __cosf(x);
    const float env = (dd < CUTOFF_F) ? (0.5f * (c1 + 1.0f)) : 0.0f;
    u_env[pos] = make_float4(rx * invd, ry * invd, rz * invd, env);

    if (MODE == 1) {
        pos_of_e[e] = pos;
    } else {
        const float s1 = F32 ? sinf(x) : __sinf(x);
        const float scale = invd * env;
        const float tc = 2.0f * c1;
        float skm2 = 0.f, skm1 = s1;
        float* g = gbuf + (size_t)pos * NRBF;
        g[0] = s1 * scale;
        #pragma unroll
        for (int k = 1; k < NRBF; ++k) {
            const float sk = fmaf(tc, skm1, -skm2);
            g[k] = sk * scale;
            skm2 = skm1; skm1 = sk;
        }
    }
}

__global__ __launch_bounds__(256) void pre_scatter_kernel(const void* r_ij, const int* nbrs,
        const int* __restrict__ flags, int* cursor, int* src_ids, float4* u_env,
        int* pos_of_e, float* gbuf, int nE, int nN, int mode) {
    int e = blockIdx.x * blockDim.x + threadIdx.x;
    if (e >= nE) return;
    const int F32 = flags[0], is64 = flags[1];
    if (mode == 2) {
        if (F32) pre_scatter_body<1,2>(r_ij, nbrs, is64, cursor, src_ids, u_env, pos_of_e, gbuf, e, nE, nN);
        else     pre_scatter_body<0,2>(r_ij, nbrs, is64, cursor, src_ids, u_env, pos_of_e, gbuf, e, nE, nN);
    } else if (mode == 1) {
        if (F32) pre_scatter_body<1,1>(r_ij, nbrs, is64, cursor, src_ids, u_env, pos_of_e, gbuf, e, nE, nN);
        else     pre_scatter_body<0,1>(r_ij, nbrs, is64, cursor, src_ids, u_env, pos_of_e, gbuf, e, nE, nN);
    } else {
        if (F32) pre_scatter_body<1,0>(r_ij, nbrs, is64, cursor, src_ids, u_env, pos_of_e, gbuf, e, nE, nN);
        else     pre_scatter_body<0,0>(r_ij, nbrs, is64, cursor, src_ids, u_env, pos_of_e, gbuf, e, nE, nN);
    }
}

// ---------- fused node MLP ----------
template<int F32>
__device__ void gemm_body(const void* __restrict__ s_j, const void* __restrict__ v_j,
                          const void* __restrict__ W1,
                          const void* __restrict__ b1, const void* __restrict__ W2,
                          const void* __restrict__ b2v, bf16* __restrict__ phi, int nN,
                          int packed) {
    __shared__ float sl[8][FEAT];
    __shared__ float hl[8][FEAT];
    __shared__ float ps[3][8][FEAT];
    const int t = threadIdx.x;
    const int n0 = blockIdx.x * 8;
    const int fch = t & 127;
    const int seg = t >> 7;        // 0..2

    if (packed) {
        #pragma unroll
        for (int n = 0; n < 8; ++n) {
            int row = n0 + n;
            if (row < nN) {
                const float vv = LD<F32>(v_j, ((size_t)row * FEAT + fch) * 3 + seg);
                phi[((size_t)row * FEAT + fch) * 6 + 3 + seg] = f2b(vv);
            }
        }
    }

    for (int idx = t; idx < 8 * FEAT; idx += 384) {
        int n = idx >> 7, k = idx & 127;
        int row = n0 + n;
        sl[n][k] = (row < nN) ? LD<F32>(s_j, (size_t)row * FEAT + k) : 0.f;
    }
    __syncthreads();

    {
        const int k0 = seg * 43;
        const int k1 = (seg == 2) ? FEAT : k0 + 43;
        float part[8] = {};
        for (int k = k0; k < k1; ++k) {
            const float w = LD<F32>(W1, (size_t)k * FEAT + fch);
            #pragma unroll
            for (int n = 0; n < 8; ++n) part[n] = fmaf(sl[n][k], w, part[n]);
        }
        #pragma unroll
        for (int n = 0; n < 8; ++n) ps[seg][n][fch] = part[n];
    }
    __syncthreads();

    for (int idx = t; idx < 8 * FEAT; idx += 384) {
        int n = idx >> 7, f = idx & 127;
        float a = ps[0][n][f] + ps[1][n][f] + ps[2][n][f] + LD<F32>(b1, f);
        float sg = F32 ? (1.0f / (1.0f + expf(-a))) : (1.0f / (1.0f + __expf(-a)));
        hl[n][f] = a * sg;
    }
    __syncthreads();

    float acc[8] = {};
    #pragma unroll 4
    for (int k = 0; k < FEAT; ++k) {
        const float w = LD<F32>(W2, (size_t)k * 384 + t);
        #pragma unroll
        for (int n = 0; n < 8; ++n) acc[n] = fmaf(hl[n][k], w, acc[n]);
    }
    const float bb = LD<F32>(b2v, t);
    #pragma unroll
    for (int n = 0; n < 8; ++n) {
        int row = n0 + n;
        if (row < nN) {
            if (packed) phi[((size_t)row * FEAT + fch) * 6 + seg] = f2b(acc[n] + bb);
            else        phi[(size_t)row * 384 + t] = f2b(acc[n] + bb);
        }
    }
}

__global__ __launch_bounds__(384) void gemm_node_kernel(const void* s_j, const void* v_j,
        const void* W1, const void* b1, const void* W2, const void* b2v, bf16* phi,
        const int* __restrict__ flags, int nN, int packed) {
    if (flags[0]) gemm_body<1>(s_j, v_j, W1, b1, W2, b2v, phi, nN, packed);
    else          gemm_body<0>(s_j, v_j, W1, b1, W2, b2v, phi, nN, packed);
}

// ---------- mode A kernels ----------
template<int F32>
__device__ void pre_ws_body(const void* __restrict__ r_ij, const float* __restrict__ WdT,
        const int* __restrict__ pos_of_e, bf16* __restrict__ ws_w, int e) {
    const float rx = LD<F32>(r_ij, (size_t)3 * e + 0);
    const float ry = LD<F32>(r_ij, (size_t)3 * e + 1);
    const float rz = LD<F32>(r_ij, (size_t)3 * e + 2);
    const float d2   = rx * rx + ry * ry + rz * rz + 3e-15f;
    const float invd = rsqrtf(d2);
    const float dd   = d2 * invd;
    const float x  = dd * KSCALE;
    const float s1 = F32 ? sinf(x) : __sinf(x);
    const float c1 = F32 ? cosf(x) : __cosf(x);
    const float env = (dd < CUTOFF_F) ? (0.5f * (c1 + 1.0f)) : 0.0f;
    const float scale = invd * env;
    float gk[NRBF];
    const float tc = 2.0f * c1;
    float skm2 = 0.f, skm1 = s1;
    gk[0] = s1 * scale;
    #pragma unroll
    for (int k = 1; k < NRBF; ++k) {
        const float sk = fmaf(tc, skm1, -skm2);
        gk[k] = sk * scale;
        skm2 = skm1; skm1 = sk;
    }
    const int pos = pos_of_e[e];
    bf16* dst = ws_w + (size_t)pos * 384;
    for (int c0 = 0; c0 < 384; c0 += 4) {
        float r[4];
        #pragma unroll
        for (int u = 0; u < 4; ++u) {
            const float* w = WdT + (size_t)(c0 + u) * 24;
            float acc = w[20] * env;
            #pragma unroll
            for (int k = 0; k < NRBF; ++k) acc = fmaf(gk[k], w[k], acc);
            r[u] = acc;
        }
        union { bf16 b[4]; uint2 u2; } pk;
        pk.b[0] = f2b(r[0]); pk.b[1] = f2b(r[1]); pk.b[2] = f2b(r[2]); pk.b[3] = f2b(r[3]);
        *(uint2*)(dst + c0) = pk.u2;
    }
}

__global__ __launch_bounds__(256) void pre_ws_kernel(const void* r_ij,
        const float* __restrict__ WdT, const int* __restrict__ pos_of_e,
        bf16* __restrict__ ws_w, const int* __restrict__ flags, int nE) {
    int e = blockIdx.x * blockDim.x + threadIdx.x;
    if (e >= nE) return;
    if (flags[0]) pre_ws_body<1>(r_ij, WdT, pos_of_e, ws_w, e);
    else          pre_ws_body<0>(r_ij, WdT, pos_of_e, ws_w, e);
}

template<int F32>
__device__ void msg_a_body(const bf16* __restrict__ ws_w, const bf16* __restrict__ phi,
        const void* __restrict__ v_j, const int* __restrict__ src_ids,
        const float4* __restrict__ u_env, const int* __restrict__ offsets,
        void* __restrict__ out, int nE, int nN) {
    const int i = blockIdx.x;
    const int f = threadIdx.x;
    int start = offsets[i];
    int end   = offsets[i + 1];
    if (start < 0) start = 0;
    if (end > nE) end = nE;

    float ds = 0.f, dv0 = 0.f, dv1 = 0.f, dv2 = 0.f;

    #pragma unroll 2
    for (int p = start; p < end; ++p) {
        const int j = src_ids[p];
        const float4 ue = u_env[p];
        const bf16* wr = ws_w + (size_t)p * 384;
        const float w0 = b2f(wr[f]);
        const float w1 = b2f(wr[FEAT + f]);
        const float w2 = b2f(wr[2 * FEAT + f]);
        const bf16* ph = phi + (size_t)j * 384;
        const float p0 = b2f(ph[f]);
        const float p1 = b2f(ph[FEAT + f]);
        const float p2 = b2f(ph[2 * FEAT + f]);
        const float vx = LD<F32>(v_j, ((size_t)j * FEAT + f) * 3 + 0);
        const float vy = LD<F32>(v_j, ((size_t)j * FEAT + f) * 3 + 1);
        const float vz = LD<F32>(v_j, ((size_t)j * FEAT + f) * 3 + 2);
        const float i0 = w0 * p0;
        const float i1 = w1 * p1;
        const float i2 = w2 * p2;
        ds += i1;
        dv0 = fmaf(i2, ue.x, fmaf(i0, vx, dv0));
        dv1 = fmaf(i2, ue.y, fmaf(i0, vy, dv1));
        dv2 = fmaf(i2, ue.z, fmaf(i0, vz, dv2));
    }

    ST<F32>(out, (size_t)i * FEAT + f, ds);
    const size_t ob = (size_t)nN * FEAT + ((size_t)i * FEAT + f) * 3;
    ST<F32>(out, ob + 0, dv0);
    ST<F32>(out, ob + 1, dv1);
    ST<F32>(out, ob + 2, dv2);
}

__global__ __launch_bounds__(128) void msg_a_kernel(const bf16* ws_w, const bf16* phi,
        const void* v_j, const int* src_ids, const float4* u_env, const int* offsets,
        const int* __restrict__ flags, void* out, int nE, int nN) {
    if (flags[0]) msg_a_body<1>(ws_w, phi, v_j, src_ids, u_env, offsets, out, nE, nN);
    else          msg_a_body<0>(ws_w, phi, v_j, src_ids, u_env, offsets, out, nE, nN);
}

// ---------- mode C message (unchanged from R11) ----------
template<int F32>
__device__ void msg_c_body(const unsigned short* __restrict__ tab, const bf16* __restrict__ rec,
        const float4* __restrict__ u4, const int* __restrict__ src_ids,
        const int* __restrict__ offsets, void* __restrict__ out, int nE, int nN) {
    const int i = blockIdx.x;
    const int f = threadIdx.x;
    int start = offsets[i];
    int end   = offsets[i + 1];
    if (start < 0) start = 0;
    if (end > nE) end = nE;

    float ds = 0.f, dv0 = 0.f, dv1 = 0.f, dv2 = 0.f;

    for (int p = start; p < end; ++p) {
        const int j = src_ids[p];
        const float4 uu = u4[p];
        const float binf = uu.w;
        int bin = (int)binf;
        if (bin > NB - 2) bin = NB - 2;
        const float fr = binf - (float)bin;
        const float m = (binf < (float)(NB - 1)) ? 1.0f : 0.0f;

        const unsigned short* T = tab + (size_t)bin * 384;
        const float t00 = us2f(T[f]);
        const float t01 = us2f(T[384 + f]);
        const float t10 = us2f(T[FEAT + f]);
        const float t11 = us2f(T[384 + FEAT + f]);
        const float t20 = us2f(T[2 * FEAT + f]);
        const float t21 = us2f(T[384 + 2 * FEAT + f]);
        const float w0 = fmaf(t01 - t00, fr, t00) * m;
        const float w1 = fmaf(t11 - t10, fr, t10) * m;
        const float w2 = fmaf(t21 - t20, fr, t20) * m;

        const unsigned* rp = (const unsigned*)(rec + ((size_t)j * FEAT + f) * 6);
        const unsigned ra = rp[0];
        const unsigned rb = rp[1];
        const unsigned rc = rp[2];
        const float p0 = __uint_as_float(ra << 16);
        const float p1 = __uint_as_float(ra & 0xffff0000u);
        const float p2 = __uint_as_float(rb << 16);
        const float vx = __uint_as_float(rb & 0xffff0000u);
        const float vy = __uint_as_float(rc << 16);
        const float vz = __uint_as_float(rc & 0xffff0000u);

        const float i0 = w0 * p0;
        const float i1 = w1 * p1;
        const float i2 = w2 * p2;
        ds += i1;
        dv0 = fmaf(i2, uu.x, fmaf(i0, vx, dv0));
        dv1 = fmaf(i2, uu.y, fmaf(i0, vy, dv1));
        dv2 = fmaf(i2, uu.z, fmaf(i0, vz, dv2));
    }

    ST<F32>(out, (size_t)i * FEAT + f, ds);
    const size_t ob = (size_t)nN * FEAT + ((size_t)i * FEAT + f) * 3;
    ST<F32>(out, ob + 0, dv0);
    ST<F32>(out, ob + 1, dv1);
    ST<F32>(out, ob + 2, dv2);
}

__global__ __launch_bounds__(128) void msg_c_kernel(const unsigned short* tab, const bf16* rec,
        const float4* u4, const int* src_ids, const int* offsets,
        const int* __restrict__ flags, void* out, int nE, int nN) {
    if (flags[0]) msg_c_body<1>(tab, rec, u4, src_ids, offsets, out, nE, nN);
    else          msg_c_body<0>(tab, rec, u4, src_ids, offsets, out, nE, nN);
}

// ---------- mode B message (fallback) ----------
template<int F32>
__device__ void msg_b_body(const void* __restrict__ v_j, const void* __restrict__ Wd,
        const void* __restrict__ bd, const bf16* __restrict__ phi,
        const float* __restrict__ gbuf, const int* __restrict__ src_ids,
        const float4* __restrict__ u_env, const int* __restrict__ offsets,
        void* __restrict__ out, int nE, int nN) {
    const int i = blockIdx.x;
    const int f = threadIdx.x;

    float wd0[NRBF], wd1[NRBF], wd2[NRBF];
    #pragma unroll
    for (int k = 0; k < NRBF; ++k) {
        wd0[k] = LD<F32>(Wd, (size_t)k * 384 + f);
        wd1[k] = LD<F32>(Wd, (size_t)k * 384 + FEAT + f);
        wd2[k] = LD<F32>(Wd, (size_t)k * 384 + 2 * FEAT + f);
    }
    const float bd0 = LD<F32>(bd, f);
    const float bd1 = LD<F32>(bd, FEAT + f);
    const float bd2 = LD<F32>(bd, 2 * FEAT + f);

    int start = offsets[i];
    int end   = offsets[i + 1];
    if (start < 0) start = 0;
    if (end > nE) end = nE;

    float ds = 0.f, dv0 = 0.f, dv1 = 0.f, dv2 = 0.f;

    for (int p = start; p < end; ++p) {
        const int j = src_ids[p];
        const float4 ue = u_env[p];
        const float* g = gbuf + (size_t)p * NRBF;
        float t0 = 0.f, t1 = 0.f, t2 = 0.f;
        #pragma unroll
        for (int k = 0; k < NRBF; ++k) {
            const float gk = g[k];
            t0 = fmaf(gk, wd0[k], t0);
            t1 = fmaf(gk, wd1[k], t1);
            t2 = fmaf(gk, wd2[k], t2);
        }
        const float w0 = fmaf(bd0, ue.w, t0);
        const float w1 = fmaf(bd1, ue.w, t1);
        const float w2 = fmaf(bd2, ue.w, t2);

        const bf16* ph = phi + (size_t)j * 384;
        const float p0 = b2f(ph[f]);
        const float p1 = b2f(ph[FEAT + f]);
        const float p2 = b2f(ph[2 * FEAT + f]);
        const float vx = LD<F32>(v_j, ((size_t)j * FEAT + f) * 3 + 0);
        const float vy = LD<F32>(v_j, ((size_t)j * FEAT + f) * 3 + 1);
        const float vz = LD<F32>(v_j, ((size_t)j * FEAT + f) * 3 + 2);

        const float i0 = w0 * p0;
        const float i1 = w1 * p1;
        const float i2 = w2 * p2;
        ds += i1;
        dv0 = fmaf(i2, ue.x, fmaf(i0, vx, dv0));
        dv1 = fmaf(i2, ue.y, fmaf(i0, vy, dv1));
        dv2 = fmaf(i2, ue.z, fmaf(i0, vz, dv2));
    }

    ST<F32>(out, (size_t)i * FEAT + f, ds);
    const size_t ob = (size_t)nN * FEAT + ((size_t)i * FEAT + f) * 3;
    ST<F32>(out, ob + 0, dv0);
    ST<F32>(out, ob + 1, dv1);
    ST<F32>(out, ob + 2, dv2);
}

__global__ __launch_bounds__(128) void msg_b_kernel(const void* v_j, const void* Wd,
        const void* bd, const bf16* phi, const float* gbuf, const int* src_ids,
        const float4* u_env, const int* offsets, const int* __restrict__ flags,
        void* out, int nE, int nN) {
    if (flags[0]) msg_b_body<1>(v_j, Wd, bd, phi, gbuf, src_ids, u_env, offsets, out, nE, nN);
    else          msg_b_body<0>(v_j, Wd, bd, phi, gbuf, src_ids, u_env, offsets, out, nE, nN);
}

extern "C" void kernel_launch(void* const* d_in, const int* in_sizes, int n_in,
                              void* d_out, int out_size, void* d_ws, size_t ws_size,
                              hipStream_t stream) {
    const void* s_j  = d_in[0];
    const void* v_j  = d_in[1];
    const void* r_ij = d_in[2];
    const int*  nbrs = (const int*)d_in[3];
    const void* W1   = d_in[4];
    const void* b1   = d_in[5];
    const void* W2   = d_in[6];
    const void* b2   = d_in[7];
    const void* Wd   = d_in[8];
    const void* bd   = d_in[9];

    const int nN = out_size / (4 * FEAT);   // 20000
    const int nE = in_sizes[2] / 3;         // 640000

    char* ws = (char*)d_ws;
    size_t off = 0;
    auto alloc = [&](size_t bytes) -> void* {
        void* p = ws + off;
        off = (off + bytes + 255) & ~(size_t)255;
        return p;
    };
    int*    flags    = (int*)alloc(16);
    int*    counts   = (int*)alloc((size_t)nN * 4);
    int*    offsets  = (int*)alloc(((size_t)nN + 1) * 4);
    int*    cursor   = (int*)alloc((size_t)nN * 4);
    int*    src_ids  = (int*)alloc((size_t)nE * 4);
    float4* u_env    = (float4*)alloc((size_t)nE * 16);
    int*    partials = (int*)alloc(4096 * 4);
    float*  WdT      = (float*)alloc((size_t)384 * 24 * 4);
    const size_t base = off;

    // mode A layout: pos_of_e | phi | ws_w
    size_t offA = base;
    int*  pos_of_e = (int*)(ws + offA);  offA += ((size_t)nE * 4 + 255) & ~(size_t)255;
    bf16* phiA     = (bf16*)(ws + offA); offA += ((size_t)nN * 384 * 2 + 255) & ~(size_t)255;
    bf16* ws_w     = (bf16*)(ws + offA); offA += (size_t)nE * 384 * 2;
    // mode C layout: rec (12B per (node,f)) | tab
    size_t offC = base;
    bf16* rec = (bf16*)(ws + offC);      offC += ((size_t)nN * FEAT * 6 * 2 + 255) & ~(size_t)255;
    bf16* tab = (bf16*)(ws + offC);      offC += (size_t)NB * 384 * 2;
    // mode B layout: gbuf | phi
    size_t offB = base;
    float* gbufB = (float*)(ws + offB);  offB += ((size_t)nE * NRBF * 4 + 255) & ~(size_t)255;
    bf16*  phiB  = (bf16*)(ws + offB);   offB += (size_t)nN * 384 * 2;

    const int modeA = (ws_size >= offA) ? 1 : 0;
    const int modeC = (!modeA && ws_size >= offC) ? 1 : 0;

    if (modeC) {
        // ---- try fused cooperative CSR build ----
        bool coop_ok = false;
        hipDeviceProp_t prop;
        if (hipGetDeviceProperties(&prop, 0) == hipSuccess) {
            int perCU = 0;
            if (hipOccupancyMaxActiveBlocksPerMultiprocessor(
                    &perCU, (const void*)csr_coop_kernel, 256, 0) == hipSuccess && perCU > 0) {
                int blocks = perCU * prop.multiProcessorCount;
                if (blocks > 4096) blocks = 4096;
                const long long tot = (long long)blocks * 256;
                const int ept = (int)((nE + tot - 1) / tot);
                if (blocks >= 64 && ept <= EPT_MAX) {
                    void* s_jv = (void*)s_j; void* nbv = (void*)nbrs; void* rv = (void*)r_ij;
                    void* Wdv = (void*)Wd;  void* bdv = (void*)bd;
                    int nE_ = nE, nN_ = nN;
                    void* args[] = { &s_jv, &nbv, &rv, &flags, &counts, &offsets, &cursor,
                                     &src_ids, &u_env, &Wdv, &bdv, &tab, &partials,
                                     &nE_, &nN_ };
                    hipError_t err = hipLaunchCooperativeKernel(
                        (const void*)csr_coop_kernel, dim3(blocks), dim3(256),
                        args, 0, stream);
                    coop_ok = (err == hipSuccess);
                }
            }
        }
        if (!coop_ok) {
            init_kernel<<<(nN + 255) / 256, 256, 0, stream>>>(s_j, nbrs, nE, flags, counts, nN);
            hist_kernel<<<(nE + 255) / 256, 256, 0, stream>>>(nbrs, flags, counts, nE, nN);
            scan_kernel<<<1, 1024, 0, stream>>>(counts, offsets, cursor, nN);
            pre_scatter_kernel<<<(nE + 255) / 256, 256, 0, stream>>>(
                r_ij, nbrs, flags, cursor, src_ids, u_env, pos_of_e, gbufB, nE, nN, 2);
            build_table_kernel<<<NB, 384, 0, stream>>>(Wd, bd, tab, flags);
        }
        gemm_node_kernel<<<(nN + 7) / 8, 384, 0, stream>>>(s_j, v_j, W1, b1, W2, b2, rec, flags, nN, 1);
        msg_c_kernel<<<nN, 128, 0, stream>>>((const unsigned short*)tab, rec, u_env, src_ids,
                                             offsets, flags, d_out, nE, nN);
        return;
    }

    init_kernel<<<(nN + 255) / 256, 256, 0, stream>>>(s_j, nbrs, nE, flags, counts, nN);
    hist_kernel<<<(nE + 255) / 256, 256, 0, stream>>>(nbrs, flags, counts, nE, nN);
    scan_kernel<<<1, 1024, 0, stream>>>(counts, offsets, cursor, nN);

    const int psMode = modeA ? 1 : 0;
    pre_scatter_kernel<<<(nE + 255) / 256, 256, 0, stream>>>(
        r_ij, nbrs, flags, cursor, src_ids, u_env, pos_of_e, gbufB, nE, nN, psMode);

    if (modeA) {
        prep_kernel<<<1, 384, 0, stream>>>(Wd, bd, WdT, flags);
        gemm_node_kernel<<<(nN + 7) / 8, 384, 0, stream>>>(s_j, v_j, W1, b1, W2, b2, phiA, flags, nN, 0);
        pre_ws_kernel<<<(nE + 255) / 256, 256, 0, stream>>>(r_ij, WdT, pos_of_e, ws_w, flags, nE);
        msg_a_kernel<<<nN, 128, 0, stream>>>(ws_w, phiA, v_j, src_ids, u_env, offsets,
                                             flags, d_out, nE, nN);
    } else {
        gemm_node_kernel<<<(nN + 7) / 8, 384, 0, stream>>>(s_j, v_j, W1, b1, W2, b2, phiB, flags, nN, 0);
        msg_b_kernel<<<nN, 128, 0, stream>>>(v_j, Wd, bd, phiB, gbufB, src_ids, u_env,
                                             offsets, flags, d_out, nE, nN);
    }
}

// Round 13
// 489.089 us; speedup vs baseline: 1.4868x; 1.4868x over previous
//
#include <hip/hip_runtime.h>
#include <hip/hip_bf16.h>
#include <math.h>

typedef __hip_bfloat16 bf16;

#define FEAT 128
#define NRBF 20
#define CUTOFF_F 5.0f
#define KSCALE 0.62831853071795864769f  // pi / 5
#define NB 4096
#define INV_H 819.0f                    // (NB-1)/CUTOFF
#define H_STEP 0.001221001221001221f    // CUTOFF/(NB-1)

__device__ __forceinline__ float b2f(bf16 x) { return __bfloat162float(x); }
__device__ __forceinline__ bf16 f2b(float x) { return __float2bfloat16(x); }
__device__ __forceinline__ float us2f(unsigned short u) {
    return __uint_as_float(((unsigned)u) << 16);
}

template<int F32>
__device__ __forceinline__ float LD(const void* p, size_t i) {
    if (F32) return ((const float*)p)[i];
    return b2f(((const bf16*)p)[i]);
}
template<int F32>
__device__ __forceinline__ void ST(void* p, size_t i, float v) {
    if (F32) ((float*)p)[i] = v;
    else ((bf16*)p)[i] = f2b(v);
}

__device__ __forceinline__ int get_dst(const int* nb, int e, int is64) {
    return is64 ? nb[4 * e] : nb[2 * e];
}
__device__ __forceinline__ int get_src(const int* nb, int e, int is64) {
    return is64 ? nb[4 * e + 2] : nb[2 * e + 1];
}
__device__ __forceinline__ int clampi(int v, int n) {
    return v < 0 ? 0 : (v >= n ? n - 1 : v);
}

// ---------- init: zero counts + sniff dtypes ----------
__global__ void init_kernel(const void* __restrict__ s_ptr, const int* __restrict__ nbrs32,
                            int nE, int* __restrict__ flags, int* __restrict__ counts, int nN) {
    int t = blockIdx.x * blockDim.x + threadIdx.x;
    if (t < nN) counts[t] = 0;
    if (t == 0) {
        const unsigned* u = (const unsigned*)s_ptr;
        int hits = 0;
        for (int i = 0; i < 64; ++i) {
            unsigned ef = (u[i] >> 7) & 0xFF;
            hits += (ef >= 110 && ef <= 135) ? 1 : 0;
        }
        flags[0] = (hits < 32) ? 1 : 0;   // 1 => f32 inputs
        int lim = 2 * nE; if (lim > 128) lim = 128;
        int allz = 1;
        for (int i = 1; i < lim; i += 2) allz &= (nbrs32[i] == 0);
        flags[1] = allz;                   // 1 => int64 nbrs
    }
}

// ---------- CSR build ----------
__global__ void hist_kernel(const int* __restrict__ nbrs, const int* __restrict__ flags,
                            int* __restrict__ counts, int nE, int nN) {
    int e = blockIdx.x * blockDim.x + threadIdx.x;
    if (e < nE) {
        int d = clampi(get_dst(nbrs, e, flags[1]), nN);
        atomicAdd(&counts[d], 1);
    }
}

__global__ __launch_bounds__(1024) void scan_kernel(const int* __restrict__ counts,
        int* __restrict__ offsets, int* __restrict__ cursor, int nN) {
    __shared__ int part[1024];
    const int t = threadIdx.x;
    const int chunk = (nN + 1023) / 1024;
    const int base = t * chunk;
    int local[32];
    int sum = 0;
    for (int c = 0; c < chunk && c < 32; ++c) {
        int idx = base + c;
        int v = (idx < nN) ? counts[idx] : 0;
        local[c] = v;
        sum += v;
    }
    part[t] = sum;
    __syncthreads();
    for (int off = 1; off < 1024; off <<= 1) {
        int add = (t >= off) ? part[t - off] : 0;
        __syncthreads();
        part[t] += add;
        __syncthreads();
    }
    int run = part[t] - sum;
    for (int c = 0; c < chunk && c < 32; ++c) {
        int idx = base + c;
        if (idx < nN) { offsets[idx] = run; cursor[idx] = run; run += local[c]; }
    }
    if (t == 1023) offsets[nN] = part[1023];
}

// ---------- prep (mode A only): WdT[c][0..19] = Wd[k][c], WdT[c][20] = bd[c] ----------
__global__ __launch_bounds__(384) void prep_kernel(const void* __restrict__ Wd,
        const void* __restrict__ bd, float* __restrict__ WdT, const int* __restrict__ flags) {
    const int c = threadIdx.x;
    const int F32 = flags[0];
    if (F32) {
        for (int k = 0; k < NRBF; ++k) WdT[c * 24 + k] = ((const float*)Wd)[k * 384 + c];
        WdT[c * 24 + 20] = ((const float*)bd)[c];
    } else {
        for (int k = 0; k < NRBF; ++k) WdT[c * 24 + k] = b2f(((const bf16*)Wd)[k * 384 + c]);
        WdT[c * 24 + 20] = b2f(((const bf16*)bd)[c]);
    }
    WdT[c * 24 + 21] = 0.f; WdT[c * 24 + 22] = 0.f; WdT[c * 24 + 23] = 0.f;
}

// ---------- mode C: w_s lookup table, direct from Wd/bd ----------
// tab[b][c] = (rbf(d_b)@Wd + bd)[c] * env(d_b),  d_b = b*H_STEP, bf16
__global__ __launch_bounds__(384) void build_table_kernel(const void* __restrict__ Wd,
        const void* __restrict__ bd, bf16* __restrict__ tab, const int* __restrict__ flags) {
    const int b = blockIdx.x;
    const int c = threadIdx.x;
    const int F32 = flags[0];
    const float d = fmaxf(b * H_STEP, 1e-7f);
    const float x = d * KSCALE;
    const float s1 = sinf(x);
    const float c1 = cosf(x);
    const float env = (d < CUTOFF_F) ? (0.5f * (c1 + 1.0f)) : 0.0f;
    const float invd = 1.0f / d;
    float g[NRBF];
    const float tc = 2.0f * c1;
    float skm2 = 0.f, skm1 = s1;
    g[0] = s1 * invd;
    #pragma unroll
    for (int k = 1; k < NRBF; ++k) {
        const float sk = fmaf(tc, skm1, -skm2);
        g[k] = sk * invd;
        skm2 = skm1; skm1 = sk;
    }
    float acc = F32 ? ((const float*)bd)[c] : b2f(((const bf16*)bd)[c]);
    #pragma unroll
    for (int k = 0; k < NRBF; ++k) {
        const float w = F32 ? ((const float*)Wd)[(size_t)k * 384 + c]
                            : b2f(((const bf16*)Wd)[(size_t)k * 384 + c]);
        acc = fmaf(g[k], w, acc);
    }
    tab[(size_t)b * 384 + c] = f2b(acc * env);
}

// ---------- scatter + per-position side records ----------
// MODE 0 (B): src_ids + u_env{unit,env} + gbuf (trig here)
// MODE 1 (A): src_ids + u_env{unit,env} + pos_of_e (trig here)
// MODE 2 (C): src_ids + u4{unit,binf} fused (rsqrt only, no trig; 20B/edge scattered)
template<int F32, int MODE>
__device__ void pre_scatter_body(const void* __restrict__ r_ij, const int* __restrict__ nbrs,
        int is64, int* __restrict__ cursor, int* __restrict__ src_ids,
        float4* __restrict__ u_env, int* __restrict__ pos_of_e, float* __restrict__ gbuf,
        int e, int nE, int nN) {
    const int d = clampi(get_dst(nbrs, e, is64), nN);
    const int j = clampi(get_src(nbrs, e, is64), nN);
    int pos = atomicAdd(&cursor[d], 1);
    pos = clampi(pos, nE);
    src_ids[pos] = j;

    const float rx = LD<F32>(r_ij, (size_t)3 * e + 0);
    const float ry = LD<F32>(r_ij, (size_t)3 * e + 1);
    const float rz = LD<F32>(r_ij, (size_t)3 * e + 2);
    const float d2   = rx * rx + ry * ry + rz * rz + 3e-15f;
    const float invd = rsqrtf(d2);
    const float dd   = d2 * invd;

    if (MODE == 2) {
        u_env[pos] = make_float4(rx * invd, ry * invd, rz * invd, dd * INV_H);
        return;
    }

    const float x  = dd * KSCALE;
    const float c1 = F32 ? cosf(x) : __cosf(x);
    const float env = (dd < CUTOFF_F) ? (0.5f * (c1 + 1.0f)) : 0.0f;
    u_env[pos] = make_float4(rx * invd, ry * invd, rz * invd, env);

    if (MODE == 1) {
        pos_of_e[e] = pos;
    } else {
        const float s1 = F32 ? sinf(x) : __sinf(x);
        const float scale = invd * env;
        const float tc = 2.0f * c1;
        float skm2 = 0.f, skm1 = s1;
        float* g = gbuf + (size_t)pos * NRBF;
        g[0] = s1 * scale;
        #pragma unroll
        for (int k = 1; k < NRBF; ++k) {
            const float sk = fmaf(tc, skm1, -skm2);
            g[k] = sk * scale;
            skm2 = skm1; skm1 = sk;
        }
    }
}

__global__ __launch_bounds__(256) void pre_scatter_kernel(const void* r_ij, const int* nbrs,
        const int* __restrict__ flags, int* cursor, int* src_ids, float4* u_env,
        int* pos_of_e, float* gbuf, int nE, int nN, int mode) {
    int e = blockIdx.x * blockDim.x + threadIdx.x;
    if (e >= nE) return;
    const int F32 = flags[0], is64 = flags[1];
    if (mode == 2) {
        if (F32) pre_scatter_body<1,2>(r_ij, nbrs, is64, cursor, src_ids, u_env, pos_of_e, gbuf, e, nE, nN);
        else     pre_scatter_body<0,2>(r_ij, nbrs, is64, cursor, src_ids, u_env, pos_of_e, gbuf, e, nE, nN);
    } else if (mode == 1) {
        if (F32) pre_scatter_body<1,1>(r_ij, nbrs, is64, cursor, src_ids, u_env, pos_of_e, gbuf, e, nE, nN);
        else     pre_scatter_body<0,1>(r_ij, nbrs, is64, cursor, src_ids, u_env, pos_of_e, gbuf, e, nE, nN);
    } else {
        if (F32) pre_scatter_body<1,0>(r_ij, nbrs, is64, cursor, src_ids, u_env, pos_of_e, gbuf, e, nE, nN);
        else     pre_scatter_body<0,0>(r_ij, nbrs, is64, cursor, src_ids, u_env, pos_of_e, gbuf, e, nE, nN);
    }
}

// ---------- fused node MLP: phi = silu(s@W1+b1)@W2 + b2 ----------
// W1 stage k-split 3 ways (thread=(f,seg)); each W1 element loaded ONCE per
// block (64KB vs 512KB L2 traffic). Partials reduced via 12KB LDS.
// packed=1: rec[node][f][6] slots 0..2 = phi012, slots 3..5 = v_j (bf16)
template<int F32>
__device__ void gemm_body(const void* __restrict__ s_j, const void* __restrict__ v_j,
                          const void* __restrict__ W1,
                          const void* __restrict__ b1, const void* __restrict__ W2,
                          const void* __restrict__ b2v, bf16* __restrict__ phi, int nN,
                          int packed) {
    __shared__ float sl[8][FEAT];
    __shared__ float hl[8][FEAT];
    __shared__ float ps[3][8][FEAT];
    const int t = threadIdx.x;
    const int n0 = blockIdx.x * 8;
    const int fch = t & 127;
    const int seg = t >> 7;        // 0..2

    if (packed) {
        #pragma unroll
        for (int n = 0; n < 8; ++n) {
            int row = n0 + n;
            if (row < nN) {
                const float vv = LD<F32>(v_j, ((size_t)row * FEAT + fch) * 3 + seg);
                phi[((size_t)row * FEAT + fch) * 6 + 3 + seg] = f2b(vv);
            }
        }
    }

    for (int idx = t; idx < 8 * FEAT; idx += 384) {
        int n = idx >> 7, k = idx & 127;
        int row = n0 + n;
        sl[n][k] = (row < nN) ? LD<F32>(s_j, (size_t)row * FEAT + k) : 0.f;
    }
    __syncthreads();

    // W1 partial dot over this seg's k-range
    {
        const int k0 = seg * 43;
        const int k1 = (seg == 2) ? FEAT : k0 + 43;
        float part[8] = {};
        for (int k = k0; k < k1; ++k) {
            const float w = LD<F32>(W1, (size_t)k * FEAT + fch);
            #pragma unroll
            for (int n = 0; n < 8; ++n) part[n] = fmaf(sl[n][k], w, part[n]);
        }
        #pragma unroll
        for (int n = 0; n < 8; ++n) ps[seg][n][fch] = part[n];
    }
    __syncthreads();

    for (int idx = t; idx < 8 * FEAT; idx += 384) {
        int n = idx >> 7, f = idx & 127;
        float a = ps[0][n][f] + ps[1][n][f] + ps[2][n][f] + LD<F32>(b1, f);
        float sg = F32 ? (1.0f / (1.0f + expf(-a))) : (1.0f / (1.0f + __expf(-a)));
        hl[n][f] = a * sg;
    }
    __syncthreads();

    float acc[8] = {};
    #pragma unroll 4
    for (int k = 0; k < FEAT; ++k) {
        const float w = LD<F32>(W2, (size_t)k * 384 + t);
        #pragma unroll
        for (int n = 0; n < 8; ++n) acc[n] = fmaf(hl[n][k], w, acc[n]);
    }
    const float bb = LD<F32>(b2v, t);
    #pragma unroll
    for (int n = 0; n < 8; ++n) {
        int row = n0 + n;
        if (row < nN) {
            if (packed) phi[((size_t)row * FEAT + fch) * 6 + seg] = f2b(acc[n] + bb);
            else        phi[(size_t)row * 384 + t] = f2b(acc[n] + bb);
        }
    }
}

__global__ __launch_bounds__(384) void gemm_node_kernel(const void* s_j, const void* v_j,
        const void* W1, const void* b1, const void* W2, const void* b2v, bf16* phi,
        const int* __restrict__ flags, int nN, int packed) {
    if (flags[0]) gemm_body<1>(s_j, v_j, W1, b1, W2, b2v, phi, nN, packed);
    else          gemm_body<0>(s_j, v_j, W1, b1, W2, b2v, phi, nN, packed);
}

// ---------- mode A: per-edge w_s GEMM ----------
template<int F32>
__device__ void pre_ws_body(const void* __restrict__ r_ij, const float* __restrict__ WdT,
        const int* __restrict__ pos_of_e, bf16* __restrict__ ws_w, int e) {
    const float rx = LD<F32>(r_ij, (size_t)3 * e + 0);
    const float ry = LD<F32>(r_ij, (size_t)3 * e + 1);
    const float rz = LD<F32>(r_ij, (size_t)3 * e + 2);
    const float d2   = rx * rx + ry * ry + rz * rz + 3e-15f;
    const float invd = rsqrtf(d2);
    const float dd   = d2 * invd;
    const float x  = dd * KSCALE;
    const float s1 = F32 ? sinf(x) : __sinf(x);
    const float c1 = F32 ? cosf(x) : __cosf(x);
    const float env = (dd < CUTOFF_F) ? (0.5f * (c1 + 1.0f)) : 0.0f;
    const float scale = invd * env;
    float gk[NRBF];
    const float tc = 2.0f * c1;
    float skm2 = 0.f, skm1 = s1;
    gk[0] = s1 * scale;
    #pragma unroll
    for (int k = 1; k < NRBF; ++k) {
        const float sk = fmaf(tc, skm1, -skm2);
        gk[k] = sk * scale;
        skm2 = skm1; skm1 = sk;
    }
    const int pos = pos_of_e[e];
    bf16* dst = ws_w + (size_t)pos * 384;
    for (int c0 = 0; c0 < 384; c0 += 4) {
        float r[4];
        #pragma unroll
        for (int u = 0; u < 4; ++u) {
            const float* w = WdT + (size_t)(c0 + u) * 24;
            float acc = w[20] * env;
            #pragma unroll
            for (int k = 0; k < NRBF; ++k) acc = fmaf(gk[k], w[k], acc);
            r[u] = acc;
        }
        union { bf16 b[4]; uint2 u2; } pk;
        pk.b[0] = f2b(r[0]); pk.b[1] = f2b(r[1]); pk.b[2] = f2b(r[2]); pk.b[3] = f2b(r[3]);
        *(uint2*)(dst + c0) = pk.u2;
    }
}

__global__ __launch_bounds__(256) void pre_ws_kernel(const void* r_ij,
        const float* __restrict__ WdT, const int* __restrict__ pos_of_e,
        bf16* __restrict__ ws_w, const int* __restrict__ flags, int nE) {
    int e = blockIdx.x * blockDim.x + threadIdx.x;
    if (e >= nE) return;
    if (flags[0]) pre_ws_body<1>(r_ij, WdT, pos_of_e, ws_w, e);
    else          pre_ws_body<0>(r_ij, WdT, pos_of_e, ws_w, e);
}

// ---------- mode A message: pure gather-accumulate ----------
template<int F32>
__device__ void msg_a_body(const bf16* __restrict__ ws_w, const bf16* __restrict__ phi,
        const void* __restrict__ v_j, const int* __restrict__ src_ids,
        const float4* __restrict__ u_env, const int* __restrict__ offsets,
        void* __restrict__ out, int nE, int nN) {
    const int i = blockIdx.x;
    const int f = threadIdx.x;
    int start = offsets[i];
    int end   = offsets[i + 1];
    if (start < 0) start = 0;
    if (end > nE) end = nE;

    float ds = 0.f, dv0 = 0.f, dv1 = 0.f, dv2 = 0.f;

    #pragma unroll 2
    for (int p = start; p < end; ++p) {
        const int j = src_ids[p];
        const float4 ue = u_env[p];
        const bf16* wr = ws_w + (size_t)p * 384;
        const float w0 = b2f(wr[f]);
        const float w1 = b2f(wr[FEAT + f]);
        const float w2 = b2f(wr[2 * FEAT + f]);
        const bf16* ph = phi + (size_t)j * 384;
        const float p0 = b2f(ph[f]);
        const float p1 = b2f(ph[FEAT + f]);
        const float p2 = b2f(ph[2 * FEAT + f]);
        const float vx = LD<F32>(v_j, ((size_t)j * FEAT + f) * 3 + 0);
        const float vy = LD<F32>(v_j, ((size_t)j * FEAT + f) * 3 + 1);
        const float vz = LD<F32>(v_j, ((size_t)j * FEAT + f) * 3 + 2);
        const float i0 = w0 * p0;
        const float i1 = w1 * p1;
        const float i2 = w2 * p2;
        ds += i1;
        dv0 = fmaf(i2, ue.x, fmaf(i0, vx, dv0));
        dv1 = fmaf(i2, ue.y, fmaf(i0, vy, dv1));
        dv2 = fmaf(i2, ue.z, fmaf(i0, vz, dv2));
    }

    ST<F32>(out, (size_t)i * FEAT + f, ds);
    const size_t ob = (size_t)nN * FEAT + ((size_t)i * FEAT + f) * 3;
    ST<F32>(out, ob + 0, dv0);
    ST<F32>(out, ob + 1, dv1);
    ST<F32>(out, ob + 2, dv2);
}

__global__ __launch_bounds__(128) void msg_a_kernel(const bf16* ws_w, const bf16* phi,
        const void* v_j, const int* src_ids, const float4* u_env, const int* offsets,
        const int* __restrict__ flags, void* out, int nE, int nN) {
    if (flags[0]) msg_a_body<1>(ws_w, phi, v_j, src_ids, u_env, offsets, out, nE, nN);
    else          msg_a_body<0>(ws_w, phi, v_j, src_ids, u_env, offsets, out, nE, nN);
}

// ---------- mode C message: table-lerp w_s + 12B packed gather; u4 precomputed ----------
template<int F32>
__device__ void msg_c_body(const unsigned short* __restrict__ tab, const bf16* __restrict__ rec,
        const float4* __restrict__ u4, const int* __restrict__ src_ids,
        const int* __restrict__ offsets, void* __restrict__ out, int nE, int nN) {
    const int i = blockIdx.x;
    const int f = threadIdx.x;
    int start = offsets[i];
    int end   = offsets[i + 1];
    if (start < 0) start = 0;
    if (end > nE) end = nE;

    float ds = 0.f, dv0 = 0.f, dv1 = 0.f, dv2 = 0.f;

    for (int p = start; p < end; ++p) {
        const int j = src_ids[p];
        const float4 uu = u4[p];           // uniform -> s_load
        const float binf = uu.w;
        int bin = (int)binf;
        if (bin > NB - 2) bin = NB - 2;
        const float fr = binf - (float)bin;
        const float m = (binf < (float)(NB - 1)) ? 1.0f : 0.0f;   // d < CUTOFF

        const unsigned short* T = tab + (size_t)bin * 384;
        const float t00 = us2f(T[f]);
        const float t01 = us2f(T[384 + f]);
        const float t10 = us2f(T[FEAT + f]);
        const float t11 = us2f(T[384 + FEAT + f]);
        const float t20 = us2f(T[2 * FEAT + f]);
        const float t21 = us2f(T[384 + 2 * FEAT + f]);
        const float w0 = fmaf(t01 - t00, fr, t00) * m;
        const float w1 = fmaf(t11 - t10, fr, t10) * m;
        const float w2 = fmaf(t21 - t20, fr, t20) * m;

        // 12B gather: {phi0,phi1,phi2,vx,vy,vz} bf16, 4B-aligned
        const unsigned* rp = (const unsigned*)(rec + ((size_t)j * FEAT + f) * 6);
        const unsigned ra = rp[0];
        const unsigned rb = rp[1];
        const unsigned rc = rp[2];
        const float p0 = __uint_as_float(ra << 16);
        const float p1 = __uint_as_float(ra & 0xffff0000u);
        const float p2 = __uint_as_float(rb << 16);
        const float vx = __uint_as_float(rb & 0xffff0000u);
        const float vy = __uint_as_float(rc << 16);
        const float vz = __uint_as_float(rc & 0xffff0000u);

        const float i0 = w0 * p0;
        const float i1 = w1 * p1;
        const float i2 = w2 * p2;
        ds += i1;
        dv0 = fmaf(i2, uu.x, fmaf(i0, vx, dv0));
        dv1 = fmaf(i2, uu.y, fmaf(i0, vy, dv1));
        dv2 = fmaf(i2, uu.z, fmaf(i0, vz, dv2));
    }

    ST<F32>(out, (size_t)i * FEAT + f, ds);
    const size_t ob = (size_t)nN * FEAT + ((size_t)i * FEAT + f) * 3;
    ST<F32>(out, ob + 0, dv0);
    ST<F32>(out, ob + 1, dv1);
    ST<F32>(out, ob + 2, dv2);
}

__global__ __launch_bounds__(128) void msg_c_kernel(const unsigned short* tab, const bf16* rec,
        const float4* u4, const int* src_ids, const int* offsets,
        const int* __restrict__ flags, void* out, int nE, int nN) {
    if (flags[0]) msg_c_body<1>(tab, rec, u4, src_ids, offsets, out, nE, nN);
    else          msg_c_body<0>(tab, rec, u4, src_ids, offsets, out, nE, nN);
}

// ---------- mode B message (fallback) ----------
template<int F32>
__device__ void msg_b_body(const void* __restrict__ v_j, const void* __restrict__ Wd,
        const void* __restrict__ bd, const bf16* __restrict__ phi,
        const float* __restrict__ gbuf, const int* __restrict__ src_ids,
        const float4* __restrict__ u_env, const int* __restrict__ offsets,
        void* __restrict__ out, int nE, int nN) {
    const int i = blockIdx.x;
    const int f = threadIdx.x;

    float wd0[NRBF], wd1[NRBF], wd2[NRBF];
    #pragma unroll
    for (int k = 0; k < NRBF; ++k) {
        wd0[k] = LD<F32>(Wd, (size_t)k * 384 + f);
        wd1[k] = LD<F32>(Wd, (size_t)k * 384 + FEAT + f);
        wd2[k] = LD<F32>(Wd, (size_t)k * 384 + 2 * FEAT + f);
    }
    const float bd0 = LD<F32>(bd, f);
    const float bd1 = LD<F32>(bd, FEAT + f);
    const float bd2 = LD<F32>(bd, 2 * FEAT + f);

    int start = offsets[i];
    int end   = offsets[i + 1];
    if (start < 0) start = 0;
    if (end > nE) end = nE;

    float ds = 0.f, dv0 = 0.f, dv1 = 0.f, dv2 = 0.f;

    for (int p = start; p < end; ++p) {
        const int j = src_ids[p];
        const float4 ue = u_env[p];
        const float* g = gbuf + (size_t)p * NRBF;
        float t0 = 0.f, t1 = 0.f, t2 = 0.f;
        #pragma unroll
        for (int k = 0; k < NRBF; ++k) {
            const float gk = g[k];
            t0 = fmaf(gk, wd0[k], t0);
            t1 = fmaf(gk, wd1[k], t1);
            t2 = fmaf(gk, wd2[k], t2);
        }
        const float w0 = fmaf(bd0, ue.w, t0);
        const float w1 = fmaf(bd1, ue.w, t1);
        const float w2 = fmaf(bd2, ue.w, t2);

        const bf16* ph = phi + (size_t)j * 384;
        const float p0 = b2f(ph[f]);
        const float p1 = b2f(ph[FEAT + f]);
        const float p2 = b2f(ph[2 * FEAT + f]);
        const float vx = LD<F32>(v_j, ((size_t)j * FEAT + f) * 3 + 0);
        const float vy = LD<F32>(v_j, ((size_t)j * FEAT + f) * 3 + 1);
        const float vz = LD<F32>(v_j, ((size_t)j * FEAT + f) * 3 + 2);

        const float i0 = w0 * p0;
        const float i1 = w1 * p1;
        const float i2 = w2 * p2;
        ds += i1;
        dv0 = fmaf(i2, ue.x, fmaf(i0, vx, dv0));
        dv1 = fmaf(i2, ue.y, fmaf(i0, vy, dv1));
        dv2 = fmaf(i2, ue.z, fmaf(i0, vz, dv2));
    }

    ST<F32>(out, (size_t)i * FEAT + f, ds);
    const size_t ob = (size_t)nN * FEAT + ((size_t)i * FEAT + f) * 3;
    ST<F32>(out, ob + 0, dv0);
    ST<F32>(out, ob + 1, dv1);
    ST<F32>(out, ob + 2, dv2);
}

__global__ __launch_bounds__(128) void msg_b_kernel(const void* v_j, const void* Wd,
        const void* bd, const bf16* phi, const float* gbuf, const int* src_ids,
        const float4* u_env, const int* offsets, const int* __restrict__ flags,
        void* out, int nE, int nN) {
    if (flags[0]) msg_b_body<1>(v_j, Wd, bd, phi, gbuf, src_ids, u_env, offsets, out, nE, nN);
    else          msg_b_body<0>(v_j, Wd, bd, phi, gbuf, src_ids, u_env, offsets, out, nE, nN);
}

extern "C" void kernel_launch(void* const* d_in, const int* in_sizes, int n_in,
                              void* d_out, int out_size, void* d_ws, size_t ws_size,
                              hipStream_t stream) {
    const void* s_j  = d_in[0];
    const void* v_j  = d_in[1];
    const void* r_ij = d_in[2];
    const int*  nbrs = (const int*)d_in[3];
    const void* W1   = d_in[4];
    const void* b1   = d_in[5];
    const void* W2   = d_in[6];
    const void* b2   = d_in[7];
    const void* Wd   = d_in[8];
    const void* bd   = d_in[9];

    const int nN = out_size / (4 * FEAT);   // 20000
    const int nE = in_sizes[2] / 3;         // 640000

    char* ws = (char*)d_ws;
    size_t off = 0;
    auto alloc = [&](size_t bytes) -> void* {
        void* p = ws + off;
        off = (off + bytes + 255) & ~(size_t)255;
        return p;
    };
    int*    flags    = (int*)alloc(16);
    int*    counts   = (int*)alloc((size_t)nN * 4);
    int*    offsets  = (int*)alloc(((size_t)nN + 1) * 4);
    int*    cursor   = (int*)alloc((size_t)nN * 4);
    int*    src_ids  = (int*)alloc((size_t)nE * 4);
    float4* u_env    = (float4*)alloc((size_t)nE * 16);
    float*  WdT      = (float*)alloc((size_t)384 * 24 * 4);
    const size_t base = off;

    // mode A layout: pos_of_e | phi | ws_w
    size_t offA = base;
    int*  pos_of_e = (int*)(ws + offA);  offA += ((size_t)nE * 4 + 255) & ~(size_t)255;
    bf16* phiA     = (bf16*)(ws + offA); offA += ((size_t)nN * 384 * 2 + 255) & ~(size_t)255;
    bf16* ws_w     = (bf16*)(ws + offA); offA += (size_t)nE * 384 * 2;
    // mode C layout: rec (12B per (node,f)) | tab
    size_t offC = base;
    bf16* rec = (bf16*)(ws + offC);      offC += ((size_t)nN * FEAT * 6 * 2 + 255) & ~(size_t)255;
    bf16* tab = (bf16*)(ws + offC);      offC += (size_t)NB * 384 * 2;
    // mode B layout: gbuf | phi
    size_t offB = base;
    float* gbufB = (float*)(ws + offB);  offB += ((size_t)nE * NRBF * 4 + 255) & ~(size_t)255;
    bf16*  phiB  = (bf16*)(ws + offB);   offB += (size_t)nN * 384 * 2;

    const int modeA = (ws_size >= offA) ? 1 : 0;
    const int modeC = (!modeA && ws_size >= offC) ? 1 : 0;

    init_kernel<<<(nN + 255) / 256, 256, 0, stream>>>(s_j, nbrs, nE, flags, counts, nN);
    hist_kernel<<<(nE + 255) / 256, 256, 0, stream>>>(nbrs, flags, counts, nE, nN);
    scan_kernel<<<1, 1024, 0, stream>>>(counts, offsets, cursor, nN);

    const int psMode = modeA ? 1 : (modeC ? 2 : 0);
    pre_scatter_kernel<<<(nE + 255) / 256, 256, 0, stream>>>(
        r_ij, nbrs, flags, cursor, src_ids, u_env, pos_of_e, gbufB, nE, nN, psMode);

    if (modeA) {
        prep_kernel<<<1, 384, 0, stream>>>(Wd, bd, WdT, flags);
        gemm_node_kernel<<<(nN + 7) / 8, 384, 0, stream>>>(s_j, v_j, W1, b1, W2, b2, phiA, flags, nN, 0);
        pre_ws_kernel<<<(nE + 255) / 256, 256, 0, stream>>>(r_ij, WdT, pos_of_e, ws_w, flags, nE);
        msg_a_kernel<<<nN, 128, 0, stream>>>(ws_w, phiA, v_j, src_ids, u_env, offsets,
                                             flags, d_out, nE, nN);
    } else if (modeC) {
        build_table_kernel<<<NB, 384, 0, stream>>>(Wd, bd, tab, flags);
        gemm_node_kernel<<<(nN + 7) / 8, 384, 0, stream>>>(s_j, v_j, W1, b1, W2, b2, rec, flags, nN, 1);
        msg_c_kernel<<<nN, 128, 0, stream>>>((const unsigned short*)tab, rec, u_env, src_ids,
                                             offsets, flags, d_out, nE, nN);
    } else {
        gemm_node_kernel<<<(nN + 7) / 8, 384, 0, stream>>>(s_j, v_j, W1, b1, W2, b2, phiB, flags, nN, 0);
        msg_b_kernel<<<nN, 128, 0, stream>>>(v_j, Wd, bd, phiB, gbufB, src_ids, u_env,
                                             offsets, flags, d_out, nE, nN);
    }
}